// Round 8
// baseline (454.472 us; speedup 1.0000x reference)
//
#include <hip/hip_runtime.h>
#include <hip/hip_bf16.h>

// Problem constants
#define BB 8
#define TT 2048
#define DD 1024   // d_model
#define FF 1024   // ff dim

typedef __attribute__((ext_vector_type(8))) short bf16x8;
typedef __attribute__((ext_vector_type(4))) float f32x4;
typedef __attribute__((ext_vector_type(4))) short s16x4;

constexpr float kScaleLog2e = 0.03125f * 1.44269504088896340736f;

__device__ __forceinline__ short bf16_bits(float x) {
    __hip_bfloat16 h = __float2bfloat16(x);
    short s;
    __builtin_memcpy(&s, &h, sizeof(short));
    return s;
}

// ---------------------------------------------------------------------------
// Merged f32 -> bf16 convert: seq (8192 blocks) + Wq/Wk/Wv (512 each).
// ---------------------------------------------------------------------------
__global__ __launch_bounds__(256) void cvt_all(
    const float* __restrict__ seq, const float* __restrict__ Wq,
    const float* __restrict__ Wk, const float* __restrict__ Wv,
    short* __restrict__ seqb, short* __restrict__ Wb)
{
    const int bid = blockIdx.x;
    const float* src;
    short* dst;
    int i;
    if (bid < 8192)      { src = seq; dst = seqb;                      i = bid * 256 + threadIdx.x; }
    else if (bid < 8704) { src = Wq;  dst = Wb;                        i = (bid - 8192) * 256 + threadIdx.x; }
    else if (bid < 9216) { src = Wk;  dst = Wb + (size_t)FF * DD;      i = (bid - 8704) * 256 + threadIdx.x; }
    else                 { src = Wv;  dst = Wb + (size_t)2 * FF * DD;  i = (bid - 9216) * 256 + threadIdx.x; }
    f32x4 a = ((const f32x4*)src)[2 * i];
    f32x4 b = ((const f32x4*)src)[2 * i + 1];
    bf16x8 o;
#pragma unroll
    for (int j = 0; j < 4; ++j) { o[j] = bf16_bits(a[j]); o[4 + j] = bf16_bits(b[j]); }
    ((bf16x8*)dst)[i] = o;
}

// ---------------------------------------------------------------------------
// Shared bf16 GEMM core, BK=32, conflict-free swizzle:
// C[128x128] = A[128xK] @ B[128xK]^T (both K-major).
// 256 thr = 4 waves (2x2); wave = 64x64 via 4x4 MFMA subtiles.
// LDS [128][32] bf16 per operand (16 KB total -> round-6 occupancy).
// Swizzle: LDS chunk c_lds at row R holds global chunk (c_lds - (R>>1))&3;
// reader of global chunk qd uses c_lds = (qd + (R>>1))&3. The 16 lanes of a
// quad then cover all 8 (row-parity, chunk) bank combos twice -> 2-way = free
// (m136). (Rotation by R (not R>>1) would be 4-way: lanes r,r+4,r+8,r+12
// collide.)  Staging via global_load_lds width=16, lane-contiguous (m104).
// ---------------------------------------------------------------------------
__device__ __forceinline__ void gemm_core(
    const short* __restrict__ A, int lda, int m0,
    const short* __restrict__ B, int ldb, int n0,
    int K, short* As, short* Bs, f32x4 acc[4][4])
{
    const int tid  = threadIdx.x;
    const int lane = tid & 63;
    const int w    = tid >> 6;
    const int wm   = (w & 1) * 64;
    const int wn   = (w >> 1) * 64;
    const int r    = lane & 15;
    const int qd   = lane >> 4;

    for (int k0 = 0; k0 < K; k0 += 32) {
        __syncthreads();
#pragma unroll
        for (int it = 0; it < 2; ++it) {
            const int s   = tid + it * 256;
            const int row = s >> 2;
            const int cg  = ((s & 3) - (row >> 1)) & 3;   // global chunk for this slot
            const int col = cg << 3;
            __builtin_amdgcn_global_load_lds(
                (const __attribute__((address_space(1))) unsigned int*)
                    (A + (size_t)(m0 + row) * lda + k0 + col),
                (__attribute__((address_space(3))) unsigned int*)(As + s * 8),
                16, 0, 0);
            __builtin_amdgcn_global_load_lds(
                (const __attribute__((address_space(1))) unsigned int*)
                    (B + (size_t)(n0 + row) * ldb + k0 + col),
                (__attribute__((address_space(3))) unsigned int*)(Bs + s * 8),
                16, 0, 0);
        }
        __syncthreads();
        bf16x8 af[4], bf[4];
#pragma unroll
        for (int m = 0; m < 4; ++m) {
            const int R = wm + m * 16 + r;
            af[m] = *(const bf16x8*)(As + R * 32 + (((qd + (R >> 1)) & 3) << 3));
        }
#pragma unroll
        for (int n = 0; n < 4; ++n) {
            const int R = wn + n * 16 + r;
            bf[n] = *(const bf16x8*)(Bs + R * 32 + (((qd + (R >> 1)) & 3) << 3));
        }
#pragma unroll
        for (int m = 0; m < 4; ++m)
#pragma unroll
            for (int n = 0; n < 4; ++n)
                acc[m][n] = __builtin_amdgcn_mfma_f32_16x16x32_bf16(af[m], bf[n], acc[m][n], 0, 0, 0);
    }
}

// ---------------------------------------------------------------------------
// Kernel 1: q/k = seqb @ Wb^T + bias (bf16 in/out); v transposed vT[b][f][t].
// Grid 3072: nt/proj fastest (24 consecutive blocks share the A row-stripe).
// ---------------------------------------------------------------------------
__global__ __launch_bounds__(256) void qkv_tiled(
    const short* __restrict__ seqb, const short* __restrict__ Wb,
    const float* __restrict__ bq, const float* __restrict__ bk,
    const float* __restrict__ bv,
    __hip_bfloat16* __restrict__ q, __hip_bfloat16* __restrict__ k,
    __hip_bfloat16* __restrict__ vT)
{
    __shared__ short As[128 * 32], Bs[128 * 32];
    const int bid  = blockIdx.x;
    const int mt   = bid / 24;
    const int rest = bid % 24;
    const int nt   = rest & 7;
    const int proj = rest >> 3;

    const short* W    = Wb + (size_t)proj * FF * DD;
    const float* bias = proj == 0 ? bq : (proj == 1 ? bk : bv);

    f32x4 acc[4][4];
#pragma unroll
    for (int m = 0; m < 4; ++m)
#pragma unroll
        for (int n = 0; n < 4; ++n) acc[m][n] = (f32x4){0.f, 0.f, 0.f, 0.f};

    gemm_core(seqb, DD, mt * 128, W, DD, nt * 128, DD, As, Bs, acc);

    const int lane = threadIdx.x & 63;
    const int w    = threadIdx.x >> 6;
    const int wm   = (w & 1) * 64;
    const int wn   = (w >> 1) * 64;
    const int r    = lane & 15;
    const int qd   = lane >> 4;
    const int row_base = mt * 128 + wm + qd * 4;   // +m*16+i
    const int col_base = nt * 128 + wn + r;        // +n*16

    if (proj < 2) {
        __hip_bfloat16* dst = (proj == 0) ? q : k;
#pragma unroll
        for (int n = 0; n < 4; ++n) {
            const int col = col_base + n * 16;
            const float bv_ = bias[col];
#pragma unroll
            for (int m = 0; m < 4; ++m)
#pragma unroll
                for (int i = 0; i < 4; ++i)
                    dst[(size_t)(row_base + m * 16 + i) * FF + col] =
                        __float2bfloat16(acc[m][n][i] + bv_);
        }
    } else {
        // transposed V: lane's 4 regs = 4 consecutive t -> 8B packed store
#pragma unroll
        for (int m = 0; m < 4; ++m) {
            const int rowg = row_base + m * 16;
            const int b_   = rowg >> 11;
            const int t_   = rowg & 2047;
            __hip_bfloat16* vb = vT + (size_t)b_ * FF * TT;
#pragma unroll
            for (int n = 0; n < 4; ++n) {
                const int col = col_base + n * 16;
                const float bv_ = bias[col];
                s16x4 pack;
#pragma unroll
                for (int i = 0; i < 4; ++i) pack[i] = bf16_bits(acc[m][n][i] + bv_);
                *(s16x4*)(vb + (size_t)col * TT + t_) = pack;
            }
        }
    }
}

// ---------------------------------------------------------------------------
// Kernel 2: P[b][t][s] = exp(scale*q.k) bf16 (unnormalized), Z[b][t] += rowsum
// of bf16-rounded values.  Grid: 8 * 256 (st fastest -> q-tile reuse).
// ---------------------------------------------------------------------------
__global__ __launch_bounds__(256) void score_tiled(
    const __hip_bfloat16* __restrict__ q, const __hip_bfloat16* __restrict__ k,
    __hip_bfloat16* __restrict__ P, float* __restrict__ Z)
{
    __shared__ short As[128 * 32], Bs[128 * 32];
    const int bid = blockIdx.x;
    const int b   = bid >> 8;
    const int rem = bid & 255;
    const int tt  = rem >> 4;
    const int st  = rem & 15;

    const short* qb = (const short*)q + (size_t)b * TT * FF;
    const short* kb = (const short*)k + (size_t)b * TT * FF;

    f32x4 acc[4][4];
#pragma unroll
    for (int m = 0; m < 4; ++m)
#pragma unroll
        for (int n = 0; n < 4; ++n) acc[m][n] = (f32x4){0.f, 0.f, 0.f, 0.f};

    gemm_core(qb, FF, tt * 128, kb, FF, st * 128, FF, As, Bs, acc);

    const int lane = threadIdx.x & 63;
    const int w    = threadIdx.x >> 6;
    const int wm   = (w & 1) * 64;
    const int wn   = (w >> 1) * 64;
    const int r    = lane & 15;
    const int qd   = lane >> 4;
    const int row_base = tt * 128 + wm + qd * 4;
    const int col_base = st * 128 + wn + r;

    __hip_bfloat16* Pb = P + (size_t)b * TT * TT;
    float* Zb = Z + b * TT;

    float rs[4][4];
#pragma unroll
    for (int m = 0; m < 4; ++m)
#pragma unroll
        for (int i = 0; i < 4; ++i) rs[m][i] = 0.f;

#pragma unroll
    for (int m = 0; m < 4; ++m)
#pragma unroll
        for (int n = 0; n < 4; ++n) {
            const int col = col_base + n * 16;
#pragma unroll
            for (int i = 0; i < 4; ++i) {
                const float e = exp2f(acc[m][n][i] * kScaleLog2e);
                const __hip_bfloat16 eb = __float2bfloat16(e);
                rs[m][i] += __bfloat162float(eb);
                Pb[(size_t)(row_base + m * 16 + i) * TT + col] = eb;
            }
        }
#pragma unroll
    for (int off = 1; off < 16; off <<= 1)
#pragma unroll
        for (int m = 0; m < 4; ++m)
#pragma unroll
            for (int i = 0; i < 4; ++i) rs[m][i] += __shfl_xor(rs[m][i], off, 64);
    if (r == 0) {
#pragma unroll
        for (int m = 0; m < 4; ++m)
#pragma unroll
            for (int i = 0; i < 4; ++i)
                atomicAdd(&Zb[row_base + m * 16 + i], rs[m][i]);
    }
}

// ---------------------------------------------------------------------------
// Kernel 3: out[b][t][f] = (P @ V)/Z via vT.  Grid: 8 * 128 (ft fastest).
// ---------------------------------------------------------------------------
__global__ __launch_bounds__(256) void pv_tiled(
    const __hip_bfloat16* __restrict__ P, const __hip_bfloat16* __restrict__ vT,
    const float* __restrict__ Z, float* __restrict__ out)
{
    __shared__ short As[128 * 32], Bs[128 * 32];
    const int bid = blockIdx.x;
    const int b   = bid >> 7;
    const int rem = bid & 127;
    const int tt  = rem >> 3;
    const int ft  = rem & 7;

    const short* Pb = (const short*)P + (size_t)b * TT * TT;
    const short* vb = (const short*)vT + (size_t)b * FF * TT;

    f32x4 acc[4][4];
#pragma unroll
    for (int m = 0; m < 4; ++m)
#pragma unroll
        for (int n = 0; n < 4; ++n) acc[m][n] = (f32x4){0.f, 0.f, 0.f, 0.f};

    gemm_core(Pb, TT, tt * 128, vb, TT, ft * 128, TT, As, Bs, acc);

    const int lane = threadIdx.x & 63;
    const int w    = threadIdx.x >> 6;
    const int wm   = (w & 1) * 64;
    const int wn   = (w >> 1) * 64;
    const int r    = lane & 15;
    const int qd   = lane >> 4;
    const int row_base = tt * 128 + wm + qd * 4;
    const int col_base = ft * 128 + wn + r;

    const float* Zb = Z + b * TT;
    float* ob = out + (size_t)b * TT * FF;

#pragma unroll
    for (int m = 0; m < 4; ++m) {
        float rz[4];
#pragma unroll
        for (int i = 0; i < 4; ++i) rz[i] = 1.0f / Zb[row_base + m * 16 + i];
#pragma unroll
        for (int n = 0; n < 4; ++n) {
            const int col = col_base + n * 16;
#pragma unroll
            for (int i = 0; i < 4; ++i)
                ob[(size_t)(row_base + m * 16 + i) * FF + col] = acc[m][n][i] * rz[i];
        }
    }
}

// ---------------------------------------------------------------------------
extern "C" void kernel_launch(void* const* d_in, const int* in_sizes, int n_in,
                              void* d_out, int out_size, void* d_ws, size_t ws_size,
                              hipStream_t stream) {
    const float* seq = (const float*)d_in[0];
    const float* Wq  = (const float*)d_in[1];
    const float* bq  = (const float*)d_in[2];
    const float* Wk  = (const float*)d_in[3];
    const float* bk  = (const float*)d_in[4];
    const float* Wv  = (const float*)d_in[5];
    const float* bv  = (const float*)d_in[6];
    float* out = (float*)d_out;
    char* ws = (char*)d_ws;

    // Workspace (167,837,696 B — bound proven by round 5's tier-1):
    //   q   : 32 MiB @ 0
    //   k   : 32 MiB @ 33554432
    //   vT  : 32 MiB @ 67108864
    //   P   : 64 MiB @ 100663296   (seqb [32 MiB] + Wb [6 MiB] alias P;
    //                               both dead before score writes P)
    //   Z   : 64 KiB @ 167772160
    const size_t MB32 = 33554432;
    __hip_bfloat16* q   = (__hip_bfloat16*)(ws);
    __hip_bfloat16* k   = (__hip_bfloat16*)(ws + MB32);
    __hip_bfloat16* vT  = (__hip_bfloat16*)(ws + 2 * MB32);
    __hip_bfloat16* P   = (__hip_bfloat16*)(ws + 3 * MB32);
    float*          Z   = (float*)(ws + 3 * MB32 + (size_t)67108864);
    short*          seqb = (short*)P;
    short*          Wb   = (short*)((char*)P + MB32);

    hipMemsetAsync(Z, 0, (size_t)BB * TT * sizeof(float), stream);

    cvt_all<<<9728, 256, 0, stream>>>(seq, Wq, Wk, Wv, seqb, Wb);
    qkv_tiled<<<128 * 24, 256, 0, stream>>>(seqb, Wb, bq, bk, bv, q, k, vT);
    score_tiled<<<BB * 256, 256, 0, stream>>>(q, k, P, Z);
    pv_tiled<<<BB * 128, 256, 0, stream>>>(P, vT, Z, out);
}